// Round 13
// baseline (992.961 us; speedup 1.0000x reference)
//
#include <hip/hip_runtime.h>
#include <math.h>

// ---------------- problem constants ----------------
#define T_LEN   2880000      // samples per channel
#define LASTFR  5625         // frames t = 0..5625
#define NBLK_EQ 625          // 9 chunks per block (R9 config: proven 762.7us)
#define SEG     7680         // scan segment samples
#define NSEG    375          // segments per channel
#define KREC    15           // samples composed per record (16 slopes = 4x float4)
#define NREC    512          // records per segment (7680 / 15)
#define PROWS   528          // rows allocated per plane (prefetch max row 515)
#define RST     384          // row stride (4 pad cols + 375 + slack)
#define PL      (PROWS * RST)    // float4 elems per plane (8 planes: ch0 q0..3, ch1 q0..3)
#define SPL     (NREC * RST)     // float elems per channel state plane

typedef float2 c2;
__device__ __forceinline__ c2 cadd(c2 a, c2 b){ return make_float2(a.x+b.x, a.y+b.y); }
__device__ __forceinline__ c2 csub(c2 a, c2 b){ return make_float2(a.x-b.x, a.y-b.y); }
__device__ __forceinline__ c2 cmul(c2 a, c2 b){ return make_float2(a.x*b.x - a.y*b.y, a.x*b.y + a.y*b.x); }
__device__ __forceinline__ c2 cmulj(c2 a, c2 b){ return make_float2(a.x*b.x + a.y*b.y, a.y*b.x - a.x*b.y); }

template<int SGN>
__device__ __forceinline__ void dft8(c2 v[8]) {
    const float r = 0.70710678118654752f;
    c2 t0 = cadd(v[0], v[4]), t1 = csub(v[0], v[4]);
    c2 t2 = cadd(v[2], v[6]), t3 = csub(v[2], v[6]);
    c2 u0 = cadd(v[1], v[5]), u1 = csub(v[1], v[5]);
    c2 u2 = cadd(v[3], v[7]), u3 = csub(v[3], v[7]);
    c2 t3r = (SGN < 0) ? make_float2(t3.y, -t3.x) : make_float2(-t3.y, t3.x);
    c2 u3r = (SGN < 0) ? make_float2(u3.y, -u3.x) : make_float2(-u3.y, u3.x);
    c2 E0 = cadd(t0, t2), E2 = csub(t0, t2);
    c2 E1 = cadd(t1, t3r), E3 = csub(t1, t3r);
    c2 O0 = cadd(u0, u2), O2 = csub(u0, u2);
    c2 O1 = cadd(u1, u3r), O3 = csub(u1, u3r);
    c2 O1w = (SGN < 0) ? make_float2(r*(O1.x+O1.y), r*(O1.y-O1.x))
                       : make_float2(r*(O1.x-O1.y), r*(O1.x+O1.y));
    c2 O2w = (SGN < 0) ? make_float2(O2.y, -O2.x) : make_float2(-O2.y, O2.x);
    c2 O3w = (SGN < 0) ? make_float2(r*(O3.y-O3.x), -r*(O3.x+O3.y))
                       : make_float2(-r*(O3.x+O3.y), r*(O3.x-O3.y));
    v[0] = cadd(E0, O0);  v[4] = csub(E0, O0);
    v[1] = cadd(E1, O1w); v[5] = csub(E1, O1w);
    v[2] = cadd(E2, O2w); v[6] = csub(E2, O2w);
    v[3] = cadd(E3, O3w); v[7] = csub(E3, O3w);
}

__device__ __forceinline__ c2 shx(c2 v, int m) {
    return make_float2(__shfl_xor(v.x, m), __shfl_xor(v.y, m));
}

__device__ __forceinline__ void emit_chunk(float* __restrict__ dst, const float* __restrict__ WN,
                                           int cchunk, int tid, c2 r0, c2 r1) {
    const bool edge = (cchunk <= 2) || (cchunk >= 5626);
    #pragma unroll
    for (int q = 0; q < 2; ++q) {
        c2 rr = (q == 0) ? r0 : r1;
        int m = cchunk * 512 + (q << 8) + tid;
        float inv = 0.66666666666667f;
        if (edge) {
            int tmn = (m >= 2048) ? (((m - 2048) >> 9) + 1) : 0;
            int tmx = min(LASTFR, m >> 9);
            float wsum = 0.0f;
            for (int tt = tmn; tt <= tmx; ++tt) {
                float w = WN[m - (tt << 9)];
                wsum += w * w;
            }
            inv = (wsum > 1e-11f) ? (1.0f / wsum) : 1.0f;
        }
        int o = m - 1024;
        dst[o]         = rr.x * inv;
        dst[T_LEN + o] = rr.y * inv;
    }
}

// One EQ band: no-reorder fast convolution (R9 config, proven).
__global__ __launch_bounds__(256) void eq_band_kernel(
    const float* __restrict__ src, float* __restrict__ dst,
    const float* __restrict__ gain_db_p, const float f0)
{
    __shared__ c2 SA[2048];
    __shared__ c2 TWs2[256];
    __shared__ c2 TWs3[32];
    __shared__ float WN[2048];

    const int tid = threadIdx.x;
    const int b   = blockIdx.x;

    const float gdb   = *gain_db_p;
    const float g_lin = exp2f(gdb * 0.16609640474436813f);
    const float gm1   = g_lin - 1.0f;

    const float st2048 = 6.283185307179586f / 2048.0f;
    for (int idx = tid; idx < 2048; idx += 256) {
        WN[idx] = 0.5f - 0.5f * cosf(st2048 * (float)idx);
    }
    {
        int m = tid >> 5, j2 = tid & 31;
        float ang = (6.283185307179586f / 256.0f) * (float)(j2 * m);
        TWs2[tid] = make_float2(cosf(ang), -sinf(ang));
    }
    if (tid < 32) {
        int m = tid >> 2, j = tid & 3;
        float ang = (6.283185307179586f / 32.0f) * (float)(j * m);
        TWs3[tid] = make_float2(cosf(ang), -sinf(ang));
    }

    // per-thread register twiddles (F1/I4) and mask values — bit-identical to
    // the old TWs1[(m<<8)+tid] / MKs[(m<<8)+tid] table entries.
    c2 tw1[8];
    float mk[8];
    tw1[0] = make_float2(1.0f, 0.0f);
    #pragma unroll
    for (int m = 1; m < 8; ++m) {
        float ang = st2048 * (float)(tid * m);
        tw1[m] = make_float2(cosf(ang), -sinf(ang));
    }
    #pragma unroll
    for (int m = 0; m < 8; ++m) {
        int tt = tid;
        int bb = tt >> 2, jj = tt & 3;
        int qrev = ((jj & 1) << 1) | (jj >> 1);
        int k = (bb >> 3) + ((bb & 7) << 3) + (m << 6) + (qrev << 9);
        int kk = (k > 1024) ? (2048 - k) : k;
        float f = (float)kk * (24000.0f / 1024.0f);
        float d = (f - f0) / f0;
        mk[m] = (1.0f + gm1 * expf(-d * d)) * (1.0f / 2048.0f);
    }
    __syncthreads();

    const int t0   = max(0, 9 * b - 1);
    const int t1   = min(LASTFR, 9 * b + 10);
    const int cmin = 9 * b + 2;
    const int cmax = 9 * b + 10;

    c2 ring[8];
    #pragma unroll
    for (int q = 0; q < 8; ++q) ring[q] = make_float2(0.0f, 0.0f);

    for (int t = t0; t <= t1; ++t) {
        for (int j = tid; j < 2048; j += 256) {
            int ss = t * 512 + j - 1024;
            ss = (ss < 0) ? -ss : ss;
            ss = (ss >= T_LEN) ? (2 * T_LEN - 2 - ss) : ss;
            float w = WN[j];
            SA[j] = make_float2(src[ss] * w, src[T_LEN + ss] * w);
        }
        __syncthreads();

        c2 v[8];

        // F1
        #pragma unroll
        for (int k = 0; k < 8; ++k) v[k] = SA[tid + (k << 8)];
        dft8<-1>(v);
        #pragma unroll
        for (int m = 1; m < 8; ++m) v[m] = cmul(v[m], tw1[m]);
        #pragma unroll
        for (int m = 0; m < 8; ++m) SA[tid + (m << 8)] = v[m];
        __syncthreads();

        // F2
        {
            int c = tid >> 5, j2 = tid & 31;
            int base = (c << 8) + j2;
            #pragma unroll
            for (int k = 0; k < 8; ++k) v[k] = SA[base + (k << 5)];
            dft8<-1>(v);
            #pragma unroll
            for (int m = 1; m < 8; ++m) v[m] = cmul(v[m], TWs2[(m << 5) + j2]);
            __syncthreads();
            #pragma unroll
            for (int m = 0; m < 8; ++m) SA[(c << 8) + (m << 5) + (j2 ^ (m << 2))] = v[m];
        }
        __syncthreads();

        // F3 + F4(quad) + mask + I1(quad) + I2
        {
            int bb = tid >> 2, j = tid & 3;
            int base = bb << 5, bx = (bb & 7) << 2;
            #pragma unroll
            for (int k = 0; k < 8; ++k) v[k] = SA[base + ((k << 2) ^ bx) + j];
            dft8<-1>(v);
            #pragma unroll
            for (int m = 1; m < 8; ++m) v[m] = cmul(v[m], TWs3[(m << 2) + j]);
            #pragma unroll
            for (int m = 0; m < 8; ++m) {
                c2 w = v[m];
                c2 p = shx(w, 2);
                c2 e  = (j & 2) ? csub(p, w) : cadd(w, p);
                c2 qq = shx(e, 1);
                c2 lo = (j & 1) ? csub(qq, e) : cadd(e, qq);
                c2 hi = (j & 1) ? make_float2(qq.x - e.y, qq.y + e.x)
                                : make_float2(e.x + qq.y, e.y - qq.x);
                w = (j & 2) ? hi : lo;
                float mkv = mk[m];
                w.x *= mkv; w.y *= mkv;
                c2 p2 = shx(w, 1);
                c2 e2 = (j & 1) ? csub(p2, w) : cadd(w, p2);
                c2 q2 = shx(e2, 2);
                c2 lo2 = (j & 1) ? make_float2(e2.x - q2.y, e2.y + q2.x)
                                 : cadd(e2, q2);
                c2 hi2 = (j & 1) ? make_float2(q2.x + e2.y, q2.y - e2.x)
                                 : csub(q2, e2);
                v[m] = (j & 2) ? hi2 : lo2;
            }
            #pragma unroll
            for (int m = 1; m < 8; ++m) v[m] = cmulj(v[m], TWs3[(m << 2) + j]);
            dft8<+1>(v);
            __syncthreads();
            #pragma unroll
            for (int k = 0; k < 8; ++k) SA[base + ((k << 2) ^ bx) + j] = v[k];
        }
        __syncthreads();

        // I3
        {
            int c = tid >> 5, j2 = tid & 31;
            #pragma unroll
            for (int m = 0; m < 8; ++m) v[m] = SA[(c << 8) + (m << 5) + (j2 ^ (m << 2))];
            #pragma unroll
            for (int m = 1; m < 8; ++m) v[m] = cmulj(v[m], TWs2[(m << 5) + j2]);
            dft8<+1>(v);
            __syncthreads();
            #pragma unroll
            for (int k = 0; k < 8; ++k) SA[(c << 8) + (k << 5) + j2] = v[k];
        }
        __syncthreads();

        // I4 -> OLA ring
        {
            #pragma unroll
            for (int m = 0; m < 8; ++m) v[m] = SA[tid + (m << 8)];
            #pragma unroll
            for (int m = 1; m < 8; ++m) v[m] = cmulj(v[m], tw1[m]);
            dft8<+1>(v);
            #pragma unroll
            for (int k = 0; k < 8; ++k) {
                float w = WN[tid + (k << 8)];
                ring[k].x += v[k].x * w;
                ring[k].y += v[k].y * w;
            }
        }
        __syncthreads();

        if (t >= cmin) emit_chunk(dst, WN, t, tid, ring[0], ring[1]);
        #pragma unroll
        for (int q = 0; q < 6; ++q) ring[q] = ring[q + 2];
        ring[6] = make_float2(0.0f, 0.0f);
        ring[7] = make_float2(0.0f, 0.0f);
    }
    for (int c = t1 + 1; c <= cmax; ++c) {
        emit_chunk(dst, WN, c, tid, ring[0], ring[1]);
        #pragma unroll
        for (int q = 0; q < 6; ++q) ring[q] = ring[q + 2];
        ring[6] = make_float2(0.0f, 0.0f);
        ring[7] = make_float2(0.0f, 0.0f);
    }
}

__device__ __forceinline__ float gaval(float v, float thr, float coef) {
    float aa = fabsf(v) + 1e-8f;
    return fmaxf(6.020599913279624f * __log2f(aa) - thr, 0.0f) * coef;
}

// ---------- producer: K=15 composed records (exact max-plus DP), SoA quad planes ----------
__global__ __launch_bounds__(256) void rec15_kernel(
    const float* __restrict__ y, float4* __restrict__ rec,
    const float* __restrict__ thr_p, const float* __restrict__ ratio_p,
    const float* __restrict__ att_p, const float* __restrict__ rel_p)
{
    __shared__ float4 Lsub[32][9][4];   // [row][col8][quad], padded col dim
    const int r0 = blockIdx.x * 32;
    const int s0 = blockIdx.y * 64;
    const int c  = blockIdx.z;
    const int tid = threadIdx.x;

    float thr = *thr_p, ratio = *ratio_p;
    float A  = expf(-1.0f / ((*att_p) * 48000.0f));
    float Bc = expf(-1.0f / ((*rel_p) * 48000.0f));
    float ra = (1.0f - Bc) / (1.0f - A);
    float coef = (1.0f - 1.0f / ratio) * (1.0f - A);

    const int rr = tid & 31, cg = tid >> 5;     // compute mapping (row, col-group)
    const int orow = tid >> 3, oc8 = tid & 7;   // output mapping

    #pragma unroll 1
    for (int it = 0; it < 8; ++it) {
        int s = s0 + it * 8 + cg;
        if (s < NSEG) {
            int r = r0 + rr;
            int li = s * SEG + KREC * r;
            const float* yp = y + (long)c * T_LEN + li;
            float I[16];
            float a = gaval(yp[0], thr, coef);
            if (li == 0) a = 0.0f;
            I[0] = a; I[1] = ra * a;
            #pragma unroll
            for (int n = 1; n < KREC; ++n) {
                a = gaval(yp[n], thr, coef);
                float b = ra * a;
                I[n + 1] = fmaf(Bc, I[n], b);
                #pragma unroll
                for (int j = n; j >= 1; --j)
                    I[j] = fmaxf(fmaf(A, I[j], a), fmaf(Bc, I[j - 1], b));
                I[0] = fmaf(A, I[0], a);
            }
            Lsub[rr][cg][0] = make_float4(I[0],  I[1],  I[2],  I[3]);
            Lsub[rr][cg][1] = make_float4(I[4],  I[5],  I[6],  I[7]);
            Lsub[rr][cg][2] = make_float4(I[8],  I[9],  I[10], I[11]);
            Lsub[rr][cg][3] = make_float4(I[12], I[13], I[14], I[15]);
        }
        __syncthreads();
        int so = s0 + it * 8 + oc8;
        if (so < NSEG) {
            #pragma unroll
            for (int q = 0; q < 4; ++q)
                rec[(long)(c * 4 + q) * PL + (r0 + orow) * RST + 4 + so]
                    = Lsub[orow][oc8][q];
        }
        __syncthreads();
    }
}

// ---------- scan: iterated single-column passes, TWO independent chains/lane ----------
// Model (R0/R4/R5/R12): strided-load latency ~1800cy makes a single dependent
// chain cost 57 cy/load regardless of buffering (R3/R8/R12 all failed to beat
// it). R13: each lane owns segment s of BOTH channels - two independent p
// chains whose load streams interleave, doubling loads-in-flight per wave.
// Skeleton is R5's proven load-before-consume double-buffer with SB between
// regions, at batch=4/chain (4 buffers x 4 Rec = 256 data VGPRs, no spill).
// Per-chain record order + fmaf/fmax tree unchanged -> bit-identical.
// 375 lanes -> 6 blocks of 64 (lanes 375..383 clamp to s=374, benign dup).

struct Rec { float4 a, b, c, d; };

__device__ __forceinline__ void load4(Rec (&bb)[4],
    const float4* p0, const float4* p1, const float4* p2, const float4* p3, int r)
{
    #pragma unroll
    for (int k = 0; k < 4; ++k) {
        int o = (r + k) * RST;
        bb[k].a = p0[o]; bb[k].b = p1[o]; bb[k].c = p2[o]; bb[k].d = p3[o];
    }
}

template<bool STORE>
__device__ __forceinline__ void consume4(Rec (&bb)[4], float* sp, int r, float& p,
                                         const float (&S)[16])
{
    #pragma unroll
    for (int k = 0; k < 4; ++k) {
        Rec v = bb[k];
        float m0 = fmaxf(fmaf(S[0],  p, v.a.x), fmaf(S[1],  p, v.a.y));
        float m1 = fmaxf(fmaf(S[2],  p, v.a.z), fmaf(S[3],  p, v.a.w));
        float m2 = fmaxf(fmaf(S[4],  p, v.b.x), fmaf(S[5],  p, v.b.y));
        float m3 = fmaxf(fmaf(S[6],  p, v.b.z), fmaf(S[7],  p, v.b.w));
        float m4 = fmaxf(fmaf(S[8],  p, v.c.x), fmaf(S[9],  p, v.c.y));
        float m5 = fmaxf(fmaf(S[10], p, v.c.z), fmaf(S[11], p, v.c.w));
        float m6 = fmaxf(fmaf(S[12], p, v.d.x), fmaf(S[13], p, v.d.y));
        float m7 = fmaxf(fmaf(S[14], p, v.d.z), fmaf(S[15], p, v.d.w));
        m0 = fmaxf(m0, m1); m2 = fmaxf(m2, m3);
        m4 = fmaxf(m4, m5); m6 = fmaxf(m6, m7);
        m0 = fmaxf(m0, m2); m4 = fmaxf(m4, m6);
        p = fmaxf(m0, m4);
        if (STORE) sp[(r + k) * RST] = p;
    }
}

#define SB __builtin_amdgcn_sched_barrier(0)

template<bool STORE>
__device__ void scan_pass2(
    const float4* a00, const float4* a01, const float4* a02, const float4* a03,
    const float4* a10, const float4* a11, const float4* a12, const float4* a13,
    float* sp0, float* sp1, float& p0, float& p1, const float (&S)[16])
{
    Rec A0[4], A1[4], B0[4], B1[4];
    load4(A0, a00, a01, a02, a03, 0);
    load4(A1, a10, a11, a12, a13, 0);
    SB;
    int r = 0;
    #pragma unroll 1
    for (int gg = 0; gg < NREC / 8; ++gg) {       // 64 iters x 8 records/chain
        load4(B0, a00, a01, a02, a03, r + 4);
        load4(B1, a10, a11, a12, a13, r + 4);
        SB;
        consume4<STORE>(A0, sp0, r, p0, S);
        consume4<STORE>(A1, sp1, r, p1, S);
        SB;
        load4(A0, a00, a01, a02, a03, r + 8);     // last iter: rows 512..515 junk
        load4(A1, a10, a11, a12, a13, r + 8);
        SB;
        consume4<STORE>(B0, sp0, r + 4, p0, S);
        consume4<STORE>(B1, sp1, r + 4, p1, S);
        SB;
        r += 8;
    }
}

// MODE 0: first iter (incoming 0, write eOut). MODE 1: mid iter (read eIn, write
// eOut). MODE 2: store pass (read eIn, write per-record states to gsP).
template<int MODE>
__global__ __launch_bounds__(64, 1) void scan_iter_kernel(
    const float4* __restrict__ rec, float* __restrict__ gsP,
    const float* __restrict__ eIn, float* __restrict__ eOut,
    const float* __restrict__ att_p, const float* __restrict__ rel_p)
{
    int gid = blockIdx.x * 64 + threadIdx.x;
    int s = min(gid, NSEG - 1);

    float A  = expf(-1.0f / ((*att_p) * 48000.0f));
    float Bc = expf(-1.0f / ((*rel_p) * 48000.0f));
    float S[16];
    {
        float pa = 1.0f;
        #pragma unroll
        for (int j = 15; j >= 0; --j) { S[j] = pa; pa *= A; }   // A^(15-j)
        float pb = 1.0f;
        #pragma unroll
        for (int j = 0; j < 16; ++j) { S[j] *= pb; pb *= Bc; }  // * B^j
    }

    float p0 = 0.0f, p1 = 0.0f;
    if (MODE != 0) {
        p0 = (s == 0) ? 0.0f : eIn[s - 1];
        p1 = (s == 0) ? 0.0f : eIn[NSEG + s - 1];
    }

    const float4* a00 = rec + (long)0 * PL + 4 + s;
    const float4* a01 = rec + (long)1 * PL + 4 + s;
    const float4* a02 = rec + (long)2 * PL + 4 + s;
    const float4* a03 = rec + (long)3 * PL + 4 + s;
    const float4* a10 = rec + (long)4 * PL + 4 + s;
    const float4* a11 = rec + (long)5 * PL + 4 + s;
    const float4* a12 = rec + (long)6 * PL + 4 + s;
    const float4* a13 = rec + (long)7 * PL + 4 + s;

    if (MODE == 2) {
        float* sp0 = gsP + 4 + s;
        float* sp1 = gsP + (long)SPL + 4 + s;
        scan_pass2<true>(a00, a01, a02, a03, a10, a11, a12, a13,
                         sp0, sp1, p0, p1, S);
    } else {
        scan_pass2<false>(a00, a01, a02, a03, a10, a11, a12, a13,
                          nullptr, nullptr, p0, p1, S);
        eOut[s]        = p0;
        eOut[NSEG + s] = p1;
    }
}

// ---------- final: LDS-transposed state tile + exact per-sample reconstruction ----------
__global__ __launch_bounds__(256) void final_kernel(
    const float* __restrict__ y, const float* __restrict__ gsP, float* __restrict__ out,
    const float* __restrict__ thr_p, const float* __restrict__ ratio_p,
    const float* __restrict__ att_p, const float* __restrict__ rel_p,
    const float* __restrict__ mk_p, const float* __restrict__ sat_p)
{
    __shared__ float LP[64][34];
    const int r0 = blockIdx.x * 32;
    const int s0 = blockIdx.y * 64;
    const int c  = blockIdx.z;
    const int tid = threadIdx.x;

    float thr = *thr_p, ratio = *ratio_p, mk = *mk_p, sat = *sat_p;
    float A  = expf(-1.0f / ((*att_p) * 48000.0f));
    float Bc = expf(-1.0f / ((*rel_p) * 48000.0f));
    float ra = (1.0f - Bc) / (1.0f - A);
    float coef = (1.0f - 1.0f / ratio) * (1.0f - A);
    const float* gb = gsP + (long)c * SPL;

    // rows r0-1 .. r0+31 (33) x 64 cols; LP[ss][rr] = state before record row r0+rr
    for (int idx = tid; idx < 33 * 64; idx += 256) {
        int rr = idx >> 6, ss = idx & 63;
        int s = s0 + ss;
        float v = 0.0f;
        if (s < NSEG) {
            int row = r0 - 1 + rr;
            if (row >= 0)      v = gb[row * RST + 4 + s];
            else if (s > 0)    v = gb[(NREC - 1) * RST + 4 + s - 1];
            // else s==0,row<0 -> true initial state 0
        }
        LP[ss][rr] = v;
    }
    __syncthreads();

    #pragma unroll 1
    for (int it = 0; it < 8; ++it) {
        int idx = it * 256 + tid;
        int ss = idx >> 5, rr = idx & 31;
        int s = s0 + ss;
        if (s >= NSEG) continue;
        int r = r0 + rr;
        int li = s * SEG + KREC * r;
        const float* yp = y + (long)c * T_LEN + li;
        float* op = out + (long)c * T_LEN + li;
        float p = LP[ss][rr];
        #pragma unroll
        for (int q = 0; q < KREC; ++q) {
            float v = yp[q];
            float a = gaval(v, thr, coef);
            if (li + q == 0) a = 0.0f;
            p = fmaxf(fmaf(A, p, a), fmaf(Bc, p, ra * a));
            float aa = fabsf(v) + 1e-8f;
            float gl = exp2f((mk - p) * 0.16609640474436813f);
            float ro = aa * gl;
            ro = (v < 0.0f) ? -ro : ro;
            if (sat > 1.0f) ro = tanhf(ro * sat) / sat;
            op[q] = ro;
        }
    }
}

extern "C" void kernel_launch(void* const* d_in, const int* in_sizes, int n_in,
                              void* d_out, int out_size, void* d_ws, size_t ws_size,
                              hipStream_t stream)
{
    const float* audio = (const float*)d_in[0];
    const float* g1    = (const float*)d_in[1];
    const float* g2    = (const float*)d_in[2];
    const float* g3    = (const float*)d_in[3];
    const float* g4    = (const float*)d_in[4];
    const float* thr   = (const float*)d_in[5];
    const float* ratio = (const float*)d_in[6];
    const float* att   = (const float*)d_in[7];
    const float* rel   = (const float*)d_in[8];
    const float* mkup  = (const float*)d_in[9];
    const float* sat   = (const float*)d_in[10];

    float* out  = (float*)d_out;                       // EQ ping-pong; final output
    float* bufA = (float*)d_ws;                        // 23.04 MB
    float4* rec = (float4*)(bufA + 2 * T_LEN);         // 8 planes = 25.95 MB
    float*  gsP = (float*)(rec + 8 * (long)PL);        // 2*SPL float = 1.57 MB
    float*  eA  = gsP + 2 * (long)SPL;                 // 750 floats
    float*  eB  = eA + 2 * NSEG;                       // 750 floats

    eq_band_kernel<<<NBLK_EQ, 256, 0, stream>>>(audio, out,  g1, 100.0f);
    eq_band_kernel<<<NBLK_EQ, 256, 0, stream>>>(out,   bufA, g2, 500.0f);
    eq_band_kernel<<<NBLK_EQ, 256, 0, stream>>>(bufA,  out,  g3, 3000.0f);
    eq_band_kernel<<<NBLK_EQ, 256, 0, stream>>>(out,   bufA, g4, 10000.0f);

    dim3 tgrid(NREC / 32, (NSEG + 63) / 64, 2);        // 16 x 6 x 2
    rec15_kernel<<<tgrid, 256, 0, stream>>>(bufA, rec, thr, ratio, att, rel);

    scan_iter_kernel<0><<<6, 64, 0, stream>>>(rec, gsP, nullptr, eA, att, rel);
    scan_iter_kernel<1><<<6, 64, 0, stream>>>(rec, gsP, eA, eB, att, rel);
    scan_iter_kernel<1><<<6, 64, 0, stream>>>(rec, gsP, eB, eA, att, rel);
    scan_iter_kernel<1><<<6, 64, 0, stream>>>(rec, gsP, eA, eB, att, rel);
    scan_iter_kernel<2><<<6, 64, 0, stream>>>(rec, gsP, eB, nullptr, att, rel);

    final_kernel<<<tgrid, 256, 0, stream>>>(bufA, gsP, out,
                                            thr, ratio, att, rel, mkup, sat);
}

// Round 14
// 728.716 us; speedup vs baseline: 1.3626x; 1.3626x over previous
//
#include <hip/hip_runtime.h>
#include <math.h>

// ---------------- problem constants ----------------
#define T_LEN   2880000      // samples per channel
#define LASTFR  5625         // frames t = 0..5625
#define NBLK_EQ 625          // 9 chunks per block (R9 config: proven 762.7us)
#define SEG     7680         // scan segment samples
#define NSEG    375          // segments per channel
#define KREC    15           // samples composed per record (16 slopes = 4x float4)
#define NREC    512          // records per segment (7680 / 15)
#define PROWS   528          // rows allocated per plane (prefetch max row 519)
#define RST     384          // row stride (4 pad cols + 375 + slack)
#define PL      (PROWS * RST)    // float4 elems per plane (8 planes: ch0 q0..3, ch1 q0..3)
#define SPL     (NREC * RST)     // float elems per channel state plane

typedef float2 c2;
__device__ __forceinline__ c2 cadd(c2 a, c2 b){ return make_float2(a.x+b.x, a.y+b.y); }
__device__ __forceinline__ c2 csub(c2 a, c2 b){ return make_float2(a.x-b.x, a.y-b.y); }
__device__ __forceinline__ c2 cmul(c2 a, c2 b){ return make_float2(a.x*b.x - a.y*b.y, a.x*b.y + a.y*b.x); }
__device__ __forceinline__ c2 cmulj(c2 a, c2 b){ return make_float2(a.x*b.x + a.y*b.y, a.y*b.x - a.x*b.y); }

template<int SGN>
__device__ __forceinline__ void dft8(c2 v[8]) {
    const float r = 0.70710678118654752f;
    c2 t0 = cadd(v[0], v[4]), t1 = csub(v[0], v[4]);
    c2 t2 = cadd(v[2], v[6]), t3 = csub(v[2], v[6]);
    c2 u0 = cadd(v[1], v[5]), u1 = csub(v[1], v[5]);
    c2 u2 = cadd(v[3], v[7]), u3 = csub(v[3], v[7]);
    c2 t3r = (SGN < 0) ? make_float2(t3.y, -t3.x) : make_float2(-t3.y, t3.x);
    c2 u3r = (SGN < 0) ? make_float2(u3.y, -u3.x) : make_float2(-u3.y, u3.x);
    c2 E0 = cadd(t0, t2), E2 = csub(t0, t2);
    c2 E1 = cadd(t1, t3r), E3 = csub(t1, t3r);
    c2 O0 = cadd(u0, u2), O2 = csub(u0, u2);
    c2 O1 = cadd(u1, u3r), O3 = csub(u1, u3r);
    c2 O1w = (SGN < 0) ? make_float2(r*(O1.x+O1.y), r*(O1.y-O1.x))
                       : make_float2(r*(O1.x-O1.y), r*(O1.x+O1.y));
    c2 O2w = (SGN < 0) ? make_float2(O2.y, -O2.x) : make_float2(-O2.y, O2.x);
    c2 O3w = (SGN < 0) ? make_float2(r*(O3.y-O3.x), -r*(O3.x+O3.y))
                       : make_float2(-r*(O3.x+O3.y), r*(O3.x-O3.y));
    v[0] = cadd(E0, O0);  v[4] = csub(E0, O0);
    v[1] = cadd(E1, O1w); v[5] = csub(E1, O1w);
    v[2] = cadd(E2, O2w); v[6] = csub(E2, O2w);
    v[3] = cadd(E3, O3w); v[7] = csub(E3, O3w);
}

__device__ __forceinline__ c2 shx(c2 v, int m) {
    return make_float2(__shfl_xor(v.x, m), __shfl_xor(v.y, m));
}

__device__ __forceinline__ void emit_chunk(float* __restrict__ dst, const float* __restrict__ WN,
                                           int cchunk, int tid, c2 r0, c2 r1) {
    const bool edge = (cchunk <= 2) || (cchunk >= 5626);
    #pragma unroll
    for (int q = 0; q < 2; ++q) {
        c2 rr = (q == 0) ? r0 : r1;
        int m = cchunk * 512 + (q << 8) + tid;
        float inv = 0.66666666666667f;
        if (edge) {
            int tmn = (m >= 2048) ? (((m - 2048) >> 9) + 1) : 0;
            int tmx = min(LASTFR, m >> 9);
            float wsum = 0.0f;
            for (int tt = tmn; tt <= tmx; ++tt) {
                float w = WN[m - (tt << 9)];
                wsum += w * w;
            }
            inv = (wsum > 1e-11f) ? (1.0f / wsum) : 1.0f;
        }
        int o = m - 1024;
        dst[o]         = rr.x * inv;
        dst[T_LEN + o] = rr.y * inv;
    }
}

// One EQ band: no-reorder fast convolution (R9 config).
// R14: source stage FUSED into F1 — the old load loop wrote SA[tid+k*256],
// barrier, then F1 read exactly those elements. Load directly into v[k]
// (identical expression tree -> bit-identical floats), dft8, twiddle, write SA
// once for F2. Removes 1 barrier + 32KB LDS round trip per frame. Window values
// for the load and OLA ring hoisted to registers (same 0.5-0.5cos expression);
// WN stays in LDS only for emit_chunk's edge wsum.
__global__ __launch_bounds__(256) void eq_band_kernel(
    const float* __restrict__ src, float* __restrict__ dst,
    const float* __restrict__ gain_db_p, const float f0)
{
    __shared__ c2 SA[2048];
    __shared__ c2 TWs2[256];
    __shared__ c2 TWs3[32];
    __shared__ float WN[2048];

    const int tid = threadIdx.x;
    const int b   = blockIdx.x;

    const float gdb   = *gain_db_p;
    const float g_lin = exp2f(gdb * 0.16609640474436813f);
    const float gm1   = g_lin - 1.0f;

    const float st2048 = 6.283185307179586f / 2048.0f;
    for (int idx = tid; idx < 2048; idx += 256) {
        WN[idx] = 0.5f - 0.5f * cosf(st2048 * (float)idx);
    }
    {
        int m = tid >> 5, j2 = tid & 31;
        float ang = (6.283185307179586f / 256.0f) * (float)(j2 * m);
        TWs2[tid] = make_float2(cosf(ang), -sinf(ang));
    }
    if (tid < 32) {
        int m = tid >> 2, j = tid & 3;
        float ang = (6.283185307179586f / 32.0f) * (float)(j * m);
        TWs3[tid] = make_float2(cosf(ang), -sinf(ang));
    }

    // per-thread register window / twiddles (F1/I4) / mask — bit-identical
    // expressions to the WN / old TWs1 / old MKs table entries.
    float wn[8];
    #pragma unroll
    for (int k = 0; k < 8; ++k)
        wn[k] = 0.5f - 0.5f * cosf(st2048 * (float)(tid + (k << 8)));
    c2 tw1[8];
    float mk[8];
    tw1[0] = make_float2(1.0f, 0.0f);
    #pragma unroll
    for (int m = 1; m < 8; ++m) {
        float ang = st2048 * (float)(tid * m);
        tw1[m] = make_float2(cosf(ang), -sinf(ang));
    }
    #pragma unroll
    for (int m = 0; m < 8; ++m) {
        int tt = tid;
        int bb = tt >> 2, jj = tt & 3;
        int qrev = ((jj & 1) << 1) | (jj >> 1);
        int k = (bb >> 3) + ((bb & 7) << 3) + (m << 6) + (qrev << 9);
        int kk = (k > 1024) ? (2048 - k) : k;
        float f = (float)kk * (24000.0f / 1024.0f);
        float d = (f - f0) / f0;
        mk[m] = (1.0f + gm1 * expf(-d * d)) * (1.0f / 2048.0f);
    }
    __syncthreads();

    const int t0   = max(0, 9 * b - 1);
    const int t1   = min(LASTFR, 9 * b + 10);
    const int cmin = 9 * b + 2;
    const int cmax = 9 * b + 10;

    c2 ring[8];
    #pragma unroll
    for (int q = 0; q < 8; ++q) ring[q] = make_float2(0.0f, 0.0f);

    for (int t = t0; t <= t1; ++t) {
        c2 v[8];

        // fused source load + window + F1 (values identical to staged version)
        #pragma unroll
        for (int k = 0; k < 8; ++k) {
            int j = tid + (k << 8);
            int ss = t * 512 + j - 1024;
            ss = (ss < 0) ? -ss : ss;
            ss = (ss >= T_LEN) ? (2 * T_LEN - 2 - ss) : ss;
            float w = wn[k];
            v[k] = make_float2(src[ss] * w, src[T_LEN + ss] * w);
        }
        dft8<-1>(v);
        #pragma unroll
        for (int m = 1; m < 8; ++m) v[m] = cmul(v[m], tw1[m]);
        #pragma unroll
        for (int m = 0; m < 8; ++m) SA[tid + (m << 8)] = v[m];
        __syncthreads();

        // F2
        {
            int c = tid >> 5, j2 = tid & 31;
            int base = (c << 8) + j2;
            #pragma unroll
            for (int k = 0; k < 8; ++k) v[k] = SA[base + (k << 5)];
            dft8<-1>(v);
            #pragma unroll
            for (int m = 1; m < 8; ++m) v[m] = cmul(v[m], TWs2[(m << 5) + j2]);
            __syncthreads();
            #pragma unroll
            for (int m = 0; m < 8; ++m) SA[(c << 8) + (m << 5) + (j2 ^ (m << 2))] = v[m];
        }
        __syncthreads();

        // F3 + F4(quad) + mask + I1(quad) + I2
        {
            int bb = tid >> 2, j = tid & 3;
            int base = bb << 5, bx = (bb & 7) << 2;
            #pragma unroll
            for (int k = 0; k < 8; ++k) v[k] = SA[base + ((k << 2) ^ bx) + j];
            dft8<-1>(v);
            #pragma unroll
            for (int m = 1; m < 8; ++m) v[m] = cmul(v[m], TWs3[(m << 2) + j]);
            #pragma unroll
            for (int m = 0; m < 8; ++m) {
                c2 w = v[m];
                c2 p = shx(w, 2);
                c2 e  = (j & 2) ? csub(p, w) : cadd(w, p);
                c2 qq = shx(e, 1);
                c2 lo = (j & 1) ? csub(qq, e) : cadd(e, qq);
                c2 hi = (j & 1) ? make_float2(qq.x - e.y, qq.y + e.x)
                                : make_float2(e.x + qq.y, e.y - qq.x);
                w = (j & 2) ? hi : lo;
                float mkv = mk[m];
                w.x *= mkv; w.y *= mkv;
                c2 p2 = shx(w, 1);
                c2 e2 = (j & 1) ? csub(p2, w) : cadd(w, p2);
                c2 q2 = shx(e2, 2);
                c2 lo2 = (j & 1) ? make_float2(e2.x - q2.y, e2.y + q2.x)
                                 : cadd(e2, q2);
                c2 hi2 = (j & 1) ? make_float2(q2.x + e2.y, q2.y - e2.x)
                                 : csub(q2, e2);
                v[m] = (j & 2) ? hi2 : lo2;
            }
            #pragma unroll
            for (int m = 1; m < 8; ++m) v[m] = cmulj(v[m], TWs3[(m << 2) + j]);
            dft8<+1>(v);
            __syncthreads();
            #pragma unroll
            for (int k = 0; k < 8; ++k) SA[base + ((k << 2) ^ bx) + j] = v[k];
        }
        __syncthreads();

        // I3
        {
            int c = tid >> 5, j2 = tid & 31;
            #pragma unroll
            for (int m = 0; m < 8; ++m) v[m] = SA[(c << 8) + (m << 5) + (j2 ^ (m << 2))];
            #pragma unroll
            for (int m = 1; m < 8; ++m) v[m] = cmulj(v[m], TWs2[(m << 5) + j2]);
            dft8<+1>(v);
            __syncthreads();
            #pragma unroll
            for (int k = 0; k < 8; ++k) SA[(c << 8) + (k << 5) + j2] = v[k];
        }
        __syncthreads();

        // I4 -> OLA ring
        {
            #pragma unroll
            for (int m = 0; m < 8; ++m) v[m] = SA[tid + (m << 8)];
            #pragma unroll
            for (int m = 1; m < 8; ++m) v[m] = cmulj(v[m], tw1[m]);
            dft8<+1>(v);
            #pragma unroll
            for (int k = 0; k < 8; ++k) {
                ring[k].x += v[k].x * wn[k];
                ring[k].y += v[k].y * wn[k];
            }
        }
        __syncthreads();

        if (t >= cmin) emit_chunk(dst, WN, t, tid, ring[0], ring[1]);
        #pragma unroll
        for (int q = 0; q < 6; ++q) ring[q] = ring[q + 2];
        ring[6] = make_float2(0.0f, 0.0f);
        ring[7] = make_float2(0.0f, 0.0f);
    }
    for (int c = t1 + 1; c <= cmax; ++c) {
        emit_chunk(dst, WN, c, tid, ring[0], ring[1]);
        #pragma unroll
        for (int q = 0; q < 6; ++q) ring[q] = ring[q + 2];
        ring[6] = make_float2(0.0f, 0.0f);
        ring[7] = make_float2(0.0f, 0.0f);
    }
}

__device__ __forceinline__ float gaval(float v, float thr, float coef) {
    float aa = fabsf(v) + 1e-8f;
    return fmaxf(6.020599913279624f * __log2f(aa) - thr, 0.0f) * coef;
}

// ---------- producer: K=15 composed records (exact max-plus DP), SoA quad planes ----------
__global__ __launch_bounds__(256) void rec15_kernel(
    const float* __restrict__ y, float4* __restrict__ rec,
    const float* __restrict__ thr_p, const float* __restrict__ ratio_p,
    const float* __restrict__ att_p, const float* __restrict__ rel_p)
{
    __shared__ float4 Lsub[32][9][4];   // [row][col8][quad], padded col dim
    const int r0 = blockIdx.x * 32;
    const int s0 = blockIdx.y * 64;
    const int c  = blockIdx.z;
    const int tid = threadIdx.x;

    float thr = *thr_p, ratio = *ratio_p;
    float A  = expf(-1.0f / ((*att_p) * 48000.0f));
    float Bc = expf(-1.0f / ((*rel_p) * 48000.0f));
    float ra = (1.0f - Bc) / (1.0f - A);
    float coef = (1.0f - 1.0f / ratio) * (1.0f - A);

    const int rr = tid & 31, cg = tid >> 5;     // compute mapping (row, col-group)
    const int orow = tid >> 3, oc8 = tid & 7;   // output mapping

    #pragma unroll 1
    for (int it = 0; it < 8; ++it) {
        int s = s0 + it * 8 + cg;
        if (s < NSEG) {
            int r = r0 + rr;
            int li = s * SEG + KREC * r;
            const float* yp = y + (long)c * T_LEN + li;
            float I[16];
            float a = gaval(yp[0], thr, coef);
            if (li == 0) a = 0.0f;
            I[0] = a; I[1] = ra * a;
            #pragma unroll
            for (int n = 1; n < KREC; ++n) {
                a = gaval(yp[n], thr, coef);
                float b = ra * a;
                I[n + 1] = fmaf(Bc, I[n], b);
                #pragma unroll
                for (int j = n; j >= 1; --j)
                    I[j] = fmaxf(fmaf(A, I[j], a), fmaf(Bc, I[j - 1], b));
                I[0] = fmaf(A, I[0], a);
            }
            Lsub[rr][cg][0] = make_float4(I[0],  I[1],  I[2],  I[3]);
            Lsub[rr][cg][1] = make_float4(I[4],  I[5],  I[6],  I[7]);
            Lsub[rr][cg][2] = make_float4(I[8],  I[9],  I[10], I[11]);
            Lsub[rr][cg][3] = make_float4(I[12], I[13], I[14], I[15]);
        }
        __syncthreads();
        int so = s0 + it * 8 + oc8;
        if (so < NSEG) {
            #pragma unroll
            for (int q = 0; q < 4; ++q)
                rec[(long)(c * 4 + q) * PL + (r0 + orow) * RST + 4 + so]
                    = Lsub[orow][oc8][q];
        }
        __syncthreads();
    }
}

// ---------- scan: iterated single-column passes (R5/R9 proven structure) ----------
// Final model (R0/R4/R5/R8/R12/R13): cost = 57 cy per 16B load per WAVE, a hard
// per-wave streaming cap (independent dual chains in one wave bought zero - R13
// doubled time with half the waves). 750 lanes = 12 waves is all the
// parallelism this decomposition has; 243us is structural.

struct Rec { float4 a, b, c, d; };

__device__ __forceinline__ void load8(Rec (&bb)[8],
    const float4* p0, const float4* p1, const float4* p2, const float4* p3, int r)
{
    #pragma unroll
    for (int k = 0; k < 8; ++k) {
        int o = (r + k) * RST;
        bb[k].a = p0[o]; bb[k].b = p1[o]; bb[k].c = p2[o]; bb[k].d = p3[o];
    }
}

template<bool STORE>
__device__ __forceinline__ void consume8(Rec (&bb)[8], float* sp, int r, float& p,
                                         const float (&S)[16])
{
    #pragma unroll
    for (int k = 0; k < 8; ++k) {
        Rec v = bb[k];
        float m0 = fmaxf(fmaf(S[0],  p, v.a.x), fmaf(S[1],  p, v.a.y));
        float m1 = fmaxf(fmaf(S[2],  p, v.a.z), fmaf(S[3],  p, v.a.w));
        float m2 = fmaxf(fmaf(S[4],  p, v.b.x), fmaf(S[5],  p, v.b.y));
        float m3 = fmaxf(fmaf(S[6],  p, v.b.z), fmaf(S[7],  p, v.b.w));
        float m4 = fmaxf(fmaf(S[8],  p, v.c.x), fmaf(S[9],  p, v.c.y));
        float m5 = fmaxf(fmaf(S[10], p, v.c.z), fmaf(S[11], p, v.c.w));
        float m6 = fmaxf(fmaf(S[12], p, v.d.x), fmaf(S[13], p, v.d.y));
        float m7 = fmaxf(fmaf(S[14], p, v.d.z), fmaf(S[15], p, v.d.w));
        m0 = fmaxf(m0, m1); m2 = fmaxf(m2, m3);
        m4 = fmaxf(m4, m5); m6 = fmaxf(m6, m7);
        m0 = fmaxf(m0, m2); m4 = fmaxf(m4, m6);
        p = fmaxf(m0, m4);
        if (STORE) sp[(r + k) * RST] = p;
    }
}

template<bool STORE>
__device__ void scan_pass(const float4* p0, const float4* p1, const float4* p2,
                          const float4* p3, float* sp, float& p, const float (&S)[16])
{
    Rec bA[8], bB[8];
    load8(bA, p0, p1, p2, p3, 0);
    __builtin_amdgcn_sched_barrier(0);
    int r = 0;
    #pragma unroll 1
    for (int gg = 0; gg < NREC / 16; ++gg) {      // 32 iters x 16 records
        load8(bB, p0, p1, p2, p3, r + 8);
        __builtin_amdgcn_sched_barrier(0);
        consume8<STORE>(bA, sp, r, p, S);
        __builtin_amdgcn_sched_barrier(0);
        load8(bA, p0, p1, p2, p3, r + 16);        // last: rows 512..519 = junk, discarded
        __builtin_amdgcn_sched_barrier(0);
        consume8<STORE>(bB, sp, r + 8, p, S);
        __builtin_amdgcn_sched_barrier(0);
        r += 16;
    }
}

// MODE 0: first iter (incoming 0, write eOut). MODE 1: mid iter (read eIn, write
// eOut). MODE 2: store pass (read eIn, write per-record states to gsP).
template<int MODE>
__global__ __launch_bounds__(64, 1) void scan_iter_kernel(
    const float4* __restrict__ rec, float* __restrict__ gsP,
    const float* __restrict__ eIn, float* __restrict__ eOut,
    const float* __restrict__ att_p, const float* __restrict__ rel_p)
{
    int gid = blockIdx.x * 64 + threadIdx.x;
    int g2 = min(gid, 2 * NSEG - 1);
    int c = g2 / NSEG;
    int s = g2 - c * NSEG;

    float A  = expf(-1.0f / ((*att_p) * 48000.0f));
    float Bc = expf(-1.0f / ((*rel_p) * 48000.0f));
    float S[16];
    {
        float pa = 1.0f;
        #pragma unroll
        for (int j = 15; j >= 0; --j) { S[j] = pa; pa *= A; }   // A^(15-j)
        float pb = 1.0f;
        #pragma unroll
        for (int j = 0; j < 16; ++j) { S[j] *= pb; pb *= Bc; }  // * B^j
    }

    float p = 0.0f;
    if (MODE != 0) p = (s == 0) ? 0.0f : eIn[c * NSEG + s - 1];

    const float4* p0 = rec + (long)(c * 4 + 0) * PL + 4 + s;
    const float4* p1 = rec + (long)(c * 4 + 1) * PL + 4 + s;
    const float4* p2 = rec + (long)(c * 4 + 2) * PL + 4 + s;
    const float4* p3 = rec + (long)(c * 4 + 3) * PL + 4 + s;

    if (MODE == 2) {
        float* sbase = gsP + (long)c * SPL + 4 + s;
        scan_pass<true>(p0, p1, p2, p3, sbase, p, S);
    } else {
        scan_pass<false>(p0, p1, p2, p3, nullptr, p, S);
        eOut[c * NSEG + s] = p;
    }
}

// ---------- final: LDS-transposed state tile + exact per-sample reconstruction ----------
__global__ __launch_bounds__(256) void final_kernel(
    const float* __restrict__ y, const float* __restrict__ gsP, float* __restrict__ out,
    const float* __restrict__ thr_p, const float* __restrict__ ratio_p,
    const float* __restrict__ att_p, const float* __restrict__ rel_p,
    const float* __restrict__ mk_p, const float* __restrict__ sat_p)
{
    __shared__ float LP[64][34];
    const int r0 = blockIdx.x * 32;
    const int s0 = blockIdx.y * 64;
    const int c  = blockIdx.z;
    const int tid = threadIdx.x;

    float thr = *thr_p, ratio = *ratio_p, mk = *mk_p, sat = *sat_p;
    float A  = expf(-1.0f / ((*att_p) * 48000.0f));
    float Bc = expf(-1.0f / ((*rel_p) * 48000.0f));
    float ra = (1.0f - Bc) / (1.0f - A);
    float coef = (1.0f - 1.0f / ratio) * (1.0f - A);
    const float* gb = gsP + (long)c * SPL;

    // rows r0-1 .. r0+31 (33) x 64 cols; LP[ss][rr] = state before record row r0+rr
    for (int idx = tid; idx < 33 * 64; idx += 256) {
        int rr = idx >> 6, ss = idx & 63;
        int s = s0 + ss;
        float v = 0.0f;
        if (s < NSEG) {
            int row = r0 - 1 + rr;
            if (row >= 0)      v = gb[row * RST + 4 + s];
            else if (s > 0)    v = gb[(NREC - 1) * RST + 4 + s - 1];
            // else s==0,row<0 -> true initial state 0
        }
        LP[ss][rr] = v;
    }
    __syncthreads();

    #pragma unroll 1
    for (int it = 0; it < 8; ++it) {
        int idx = it * 256 + tid;
        int ss = idx >> 5, rr = idx & 31;
        int s = s0 + ss;
        if (s >= NSEG) continue;
        int r = r0 + rr;
        int li = s * SEG + KREC * r;
        const float* yp = y + (long)c * T_LEN + li;
        float* op = out + (long)c * T_LEN + li;
        float p = LP[ss][rr];
        #pragma unroll
        for (int q = 0; q < KREC; ++q) {
            float v = yp[q];
            float a = gaval(v, thr, coef);
            if (li + q == 0) a = 0.0f;
            p = fmaxf(fmaf(A, p, a), fmaf(Bc, p, ra * a));
            float aa = fabsf(v) + 1e-8f;
            float gl = exp2f((mk - p) * 0.16609640474436813f);
            float ro = aa * gl;
            ro = (v < 0.0f) ? -ro : ro;
            if (sat > 1.0f) ro = tanhf(ro * sat) / sat;
            op[q] = ro;
        }
    }
}

extern "C" void kernel_launch(void* const* d_in, const int* in_sizes, int n_in,
                              void* d_out, int out_size, void* d_ws, size_t ws_size,
                              hipStream_t stream)
{
    const float* audio = (const float*)d_in[0];
    const float* g1    = (const float*)d_in[1];
    const float* g2    = (const float*)d_in[2];
    const float* g3    = (const float*)d_in[3];
    const float* g4    = (const float*)d_in[4];
    const float* thr   = (const float*)d_in[5];
    const float* ratio = (const float*)d_in[6];
    const float* att   = (const float*)d_in[7];
    const float* rel   = (const float*)d_in[8];
    const float* mkup  = (const float*)d_in[9];
    const float* sat   = (const float*)d_in[10];

    float* out  = (float*)d_out;                       // EQ ping-pong; final output
    float* bufA = (float*)d_ws;                        // 23.04 MB
    float4* rec = (float4*)(bufA + 2 * T_LEN);         // 8 planes = 25.95 MB
    float*  gsP = (float*)(rec + 8 * (long)PL);        // 2*SPL float = 1.57 MB
    float*  eA  = gsP + 2 * (long)SPL;                 // 750 floats
    float*  eB  = eA + 2 * NSEG;                       // 750 floats

    eq_band_kernel<<<NBLK_EQ, 256, 0, stream>>>(audio, out,  g1, 100.0f);
    eq_band_kernel<<<NBLK_EQ, 256, 0, stream>>>(out,   bufA, g2, 500.0f);
    eq_band_kernel<<<NBLK_EQ, 256, 0, stream>>>(bufA,  out,  g3, 3000.0f);
    eq_band_kernel<<<NBLK_EQ, 256, 0, stream>>>(out,   bufA, g4, 10000.0f);

    dim3 tgrid(NREC / 32, (NSEG + 63) / 64, 2);        // 16 x 6 x 2
    rec15_kernel<<<tgrid, 256, 0, stream>>>(bufA, rec, thr, ratio, att, rel);

    scan_iter_kernel<0><<<12, 64, 0, stream>>>(rec, gsP, nullptr, eA, att, rel);
    scan_iter_kernel<1><<<12, 64, 0, stream>>>(rec, gsP, eA, eB, att, rel);
    scan_iter_kernel<1><<<12, 64, 0, stream>>>(rec, gsP, eB, eA, att, rel);
    scan_iter_kernel<1><<<12, 64, 0, stream>>>(rec, gsP, eA, eB, att, rel);
    scan_iter_kernel<2><<<12, 64, 0, stream>>>(rec, gsP, eB, nullptr, att, rel);

    final_kernel<<<tgrid, 256, 0, stream>>>(bufA, gsP, out,
                                            thr, ratio, att, rel, mkup, sat);
}